// Round 6
// baseline (229.647 us; speedup 1.0000x reference)
//
#include <hip/hip_runtime.h>
#include <hip/hip_bf16.h>
#include <stdint.h>

typedef __attribute__((ext_vector_type(8))) short bf16x8;
typedef __attribute__((ext_vector_type(4))) float f32x4;

#define NP 2048
#define NBANK 65536
#define NCHUNKS 32
#define CHUNK 2048
#define NPH 64
#define CF 261

__device__ inline short f2bf(float f) {
  __hip_bfloat16 h = __float2bfloat16(f);
  return *reinterpret_cast<short*>(&h);
}

// ---------------- fw repack: [256][261] -> [256][264] (16B rows, zero pad) --
__global__ __launch_bounds__(256) void k_repack_fw(
    const float* __restrict__ fw, float* __restrict__ fwp)
{
  int idx = blockIdx.x * 256 + threadIdx.x;      // 256*264 = 67584
  int o = idx / 264, c = idx % 264;
  fwp[idx] = (c < CF) ? fw[(size_t)o * CF + c] : 0.f;
}

// ---------------- prep: conv+resize+fusion (blocks 0..255) ------------------
// ----------------       bank->bf16+norms   (blocks 256..8447) ---------------
__global__ __launch_bounds__(512) void k_prep(
    const float* __restrict__ image, const float* __restrict__ geometry,
    const float* __restrict__ bw, const float* __restrict__ bb,
    const float* __restrict__ fwp, const float* __restrict__ fb,
    const float* __restrict__ mb,
    short* __restrict__ flatb, float* __restrict__ qsq, float* __restrict__ wgt,
    short* __restrict__ mbb, float* __restrict__ msq)
{
  __shared__ float patch[1536];
  __shared__ float fusedS[8][264];
  __shared__ float gv[40][8];
  __shared__ float gw[40][8];
  __shared__ float redS[8][8];
  int t = threadIdx.x;
  int bid = blockIdx.x;

  if (bid >= 256) {                       // ---- bank prep: 8 rows/block ----
    int row = (bid - 256) * 8 + (t >> 6);
    int lane = t & 63;
    float4 v = ((const float4*)(mb + (size_t)row * 256))[lane];
    short4 o; o.x = f2bf(v.x); o.y = f2bf(v.y); o.z = f2bf(v.z); o.w = f2bf(v.w);
    ((short4*)(mbb + (size_t)row * 256))[lane] = o;
    float s = v.x*v.x + v.y*v.y + v.z*v.z + v.w*v.w;
    #pragma unroll
    for (int m = 1; m < 64; m <<= 1) s += __shfl_xor(s, m);
    if (lane == 0) msq[row] = s;
    return;
  }

  // ---- conv part: block = (b, h, w-quad of 8 positions), 512 threads ----
  int b = bid >> 7, rem = bid & 127, h = rem >> 2, w0 = (rem & 3) * 8;

  #pragma unroll
  for (int j = 0; j < 3; j++) {           // stage 3x8x64 image patch
    int idx = t + j * 512;
    int c = idx >> 9, r = (idx >> 6) & 7, col = idx & 63;
    patch[idx] = image[(((size_t)(b*3 + c) * 256) + 8*h + r) * 256 + 8*w0 + col];
  }
  if (t >= 320 && t < 344) {              // zero pad fused[i][261..263]
    int i = (t - 320) / 3, c = 261 + (t - 320) % 3;
    fusedS[i][c] = 0.f;
  }
  if (t < 320) {                          // geo resize partials (8 subs/value)
    int v = t >> 3, sub = t & 7;
    int i = v / 5, cg = v % 5;
    int jj = w0 + i;
    float val = 0.f, ws = 0.f;
    const float* gch = geometry + (size_t)(b*5 + cg) * 65536;
    #pragma unroll
    for (int rr = 0; rr < 2; rr++) {
      int r = sub * 2 + rr;
      int gr = 8*h - 4 + r;
      float wr = 1.f - fabsf((float)r - 7.5f) * 0.125f;
      if (gr >= 0 && gr < 256) {
        const float* grow = gch + (size_t)gr * 256;
        for (int c = 0; c < 16; c++) {
          int gc = 8*jj - 4 + c;
          if (gc >= 0 && gc < 256) {
            float wc_ = 1.f - fabsf((float)c - 7.5f) * 0.125f;
            val += wr * wc_ * grow[gc];
            ws  += wr * wc_;
          }
        }
      }
    }
    gv[v][sub] = val; gw[v][sub] = ws;
  }
  __syncthreads();
  if (t < 40) {                           // combine resize partials
    int i = t / 5, cg = t % 5;
    float sv = 0.f, sw = 0.f;
    #pragma unroll
    for (int u = 0; u < 8; u++) { sv += gv[t][u]; sw += gw[t][u]; }
    fusedS[i][256 + cg] = sv / sw;
  }

  int g = t >> 8, o = t & 255;            // group g: positions 4g..4g+3
  float a4[4] = {0.f, 0.f, 0.f, 0.f};
  const float4* wo4 = (const float4*)(bw + (size_t)o * 192);
  for (int cr = 0; cr < 24; cr++) {       // conv 8x8 s8
    const float* prow = &patch[cr * 64 + g * 32];
    #pragma unroll
    for (int half = 0; half < 2; half++) {
      float4 w4 = wo4[cr*2 + half];
      #pragma unroll
      for (int e = 0; e < 4; e++) {
        float wv = (&w4.x)[e];
        int cl = half*4 + e;
        #pragma unroll
        for (int i4 = 0; i4 < 4; i4++) a4[i4] += wv * prow[i4*8 + cl];
      }
    }
  }
  float bias = bb[o];
  #pragma unroll
  for (int i4 = 0; i4 < 4; i4++) fusedS[g*4 + i4][o] = fmaxf(a4[i4] + bias, 0.f);
  __syncthreads();

  #pragma unroll
  for (int i4 = 0; i4 < 4; i4++) a4[i4] = 0.f;
  const float4* fwo4 = (const float4*)(fwp + (size_t)o * 264);
  for (int c4 = 0; c4 < 66; c4++) {       // fusion matmul
    float4 w4 = fwo4[c4];
    #pragma unroll
    for (int e = 0; e < 4; e++) {
      float wv = (&w4.x)[e];
      int c = c4*4 + e;
      #pragma unroll
      for (int i4 = 0; i4 < 4; i4++) a4[i4] += wv * fusedS[g*4 + i4][c];
    }
  }
  float fbias = fb[o];
  int lane = t & 63, wid = t >> 6;
  #pragma unroll
  for (int i4 = 0; i4 < 4; i4++) {
    a4[i4] += fbias;
    int p = b*1024 + h*32 + w0 + g*4 + i4;
    flatb[(size_t)p * 256 + o] = f2bf(a4[i4]);
    float s = a4[i4] * a4[i4];
    #pragma unroll
    for (int m = 1; m < 64; m <<= 1) s += __shfl_xor(s, m);
    if (lane == 0) redS[g*4 + i4][wid & 3] = s;
  }
  __syncthreads();
  if (t < 8) {
    float s = redS[t][0] + redS[t][1] + redS[t][2] + redS[t][3];
    int p = b*1024 + h*32 + w0 + t;
    qsq[p] = s;
    float den = fusedS[t][256+3], opa = fusedS[t][256+2], ani = fusedS[t][256+4];
    float base2 = 0.5f*den + 0.25f*(1.f - opa) + 0.25f*ani;
    wgt[p] = 1.f + 1.f/(1.f + expf(-4.f*(base2 - 0.5f)));
  }
}

// ---------------- GEMM-min v5: quad-buffered single-barrier phases ----------
// 64 phases of 32 bank-rows. Per phase: vmcnt(N) + ONE barrier -> stage(h+3)
// -> 8 ds_read_b128 + 32 MFMA (setprio) -> vmin update. No lgkm-drain
// release barrier: with 4 buffers, stage(h+3) overwrites the buffer read at
// h-1, and the phase-h barrier proves all waves passed it (m201 principle).
// LDS chunk c=0..15 of a 16KB phase buffer: wcg=c>>3, ks=c&7; lane s4,s15
// holds B-row (wcg*16+s15), k-bytes (ks*64+s4*16). Reads dense, 0 conflicts.
__global__ __launch_bounds__(256, 2) void k_distmin(
    const short* __restrict__ Aq, const short* __restrict__ Bb,
    const float* __restrict__ qsq, const float* __restrict__ msq,
    float* __restrict__ partial)
{
  __shared__ __align__(16) unsigned char sB[4][16384];
  __shared__ float msq_lds[2048];
  __shared__ float red[2][128];
  int t = threadIdx.x;
  int lane = t & 63, wid = t >> 6;
  int wr = wid >> 1, wc = wid & 1;
  const int l15 = lane & 15, l4 = lane >> 4;
  int nc = blockIdx.x, mt = blockIdx.y;
  int m0 = mt * 128;
  const size_t nchunk0 = (size_t)nc * CHUNK;
  const unsigned char* Bbyte = (const unsigned char*)Bb + nchunk0 * 512;
  const unsigned char* Abyte = (const unsigned char*)Aq;

  // stage source offsets: chunk c = wid*4 + j of each phase
  int soff[4];
  #pragma unroll
  for (int j = 0; j < 4; j++) {
    int c = wid * 4 + j;
    int wcg = c >> 3, ks = c & 7;
    soff[j] = (wcg * 16 + l15) * 512 + ks * 64 + l4 * 16;
  }

  // msq chunk -> LDS (2048 floats)
  {
    const float4* src = (const float4*)(msq + nchunk0);
    float4* dst = (float4*)msq_lds;
    dst[t] = src[t];
    dst[t + 256] = src[t + 256];
  }

  // A tile -> registers/AGPRs (compiler's choice; unified file on gfx950)
  bf16x8 af[4][8];
  #pragma unroll
  for (int mi = 0; mi < 4; mi++)
    #pragma unroll
    for (int ks = 0; ks < 8; ks++)
      af[mi][ks] = *(const bf16x8*)(Abyte +
          (size_t)(m0 + wr*64 + mi*16 + l15) * 512 + ks*64 + l4*16);

  float vmin[4][4];
  #pragma unroll
  for (int mi = 0; mi < 4; mi++)
    #pragma unroll
    for (int r = 0; r < 4; r++) vmin[mi][r] = 3.4e38f;

#define STAGE(ph) do {                                                        \
    unsigned char* lb_ = &sB[(ph) & 3][0] + wid * 4096;                       \
    const unsigned char* gb_ = Bbyte + (size_t)(ph) * 16384;                  \
    _Pragma("unroll")                                                         \
    for (int j_ = 0; j_ < 4; j_++) {                                          \
      __builtin_amdgcn_global_load_lds(                                       \
        (const __attribute__((address_space(1))) unsigned int*)(gb_ + soff[j_]), \
        (__attribute__((address_space(3))) unsigned int*)(lb_ + j_*1024),     \
        16, 0, 0);                                                            \
    }                                                                         \
  } while (0)

#define PHASE(ph, VN) do {                                                    \
    asm volatile("s_waitcnt vmcnt(" #VN ")" ::: "memory");                    \
    __builtin_amdgcn_s_barrier();                                             \
    __builtin_amdgcn_sched_barrier(0);                                        \
    if ((ph) + 3 < NPH) STAGE((ph) + 3);                                      \
    const unsigned char* buf_ = &sB[(ph) & 3][0] + wc * 8192;                 \
    float mq_ = msq_lds[(ph) * 32 + wc * 16 + l15];                           \
    f32x4 acc_[4];                                                            \
    _Pragma("unroll")                                                         \
    for (int mi = 0; mi < 4; mi++) acc_[mi] = (f32x4){0.f,0.f,0.f,0.f};       \
    __builtin_amdgcn_s_setprio(1);                                            \
    _Pragma("unroll")                                                         \
    for (int ks = 0; ks < 8; ks++) {                                          \
      bf16x8 b_ = *(const bf16x8*)(buf_ + ks*1024 + l4*256 + l15*16);         \
      _Pragma("unroll")                                                       \
      for (int mi = 0; mi < 4; mi++)                                          \
        acc_[mi] = __builtin_amdgcn_mfma_f32_16x16x32_bf16(af[mi][ks], b_, acc_[mi], 0, 0, 0); \
    }                                                                         \
    __builtin_amdgcn_s_setprio(0);                                            \
    _Pragma("unroll")                                                         \
    for (int mi = 0; mi < 4; mi++)                                            \
      _Pragma("unroll")                                                       \
      for (int r = 0; r < 4; r++)                                             \
        vmin[mi][r] = fminf(vmin[mi][r], mq_ - 2.f*acc_[mi][r]);              \
  } while (0)

  STAGE(0); STAGE(1); STAGE(2);
  __syncthreads();   // one-time full drain: af + stages 0-2 + msq_lds visible

  for (int h = 0; h < NPH - 2; h++) {
    PHASE(h, 8);
  }
  PHASE(NPH - 2, 4);
  PHASE(NPH - 1, 0);

#undef STAGE
#undef PHASE

  // deferred cross-lane min over the 16 l15 columns
  #pragma unroll
  for (int mi = 0; mi < 4; mi++)
    #pragma unroll
    for (int r = 0; r < 4; r++) {
      float v = vmin[mi][r];
      v = fminf(v, __shfl_xor(v, 1));
      v = fminf(v, __shfl_xor(v, 2));
      v = fminf(v, __shfl_xor(v, 4));
      v = fminf(v, __shfl_xor(v, 8));
      if (l15 == 0) red[wc][wr * 64 + mi * 16 + l4 * 4 + r] = v;
    }
  __syncthreads();
  if (t < 128) {
    float v = fminf(red[0][t], red[1][t]);
    float d2 = qsq[m0 + t] + v;
    partial[(size_t)(m0 + t) * NCHUNKS + nc] = fmaxf(d2, 0.f);
  }
}

// ---------------- final min + sqrt + geo weight -----------------------------
__global__ __launch_bounds__(256) void k_final(
    const float* __restrict__ partial, const float* __restrict__ wgt,
    float* __restrict__ out)
{
  int q = blockIdx.x * 256 + threadIdx.x;        // 2048
  const float4* p = (const float4*)(partial + (size_t)q * NCHUNKS);
  float v = 3.4e38f;
  #pragma unroll
  for (int j = 0; j < 8; j++) {
    float4 x = p[j];
    v = fminf(v, fminf(fminf(x.x, x.y), fminf(x.z, x.w)));
  }
  float sp = sqrtf(v);
  out[q] = sp;
  out[NP + q] = sp * wgt[q];
}

extern "C" void kernel_launch(void* const* d_in, const int* in_sizes, int n_in,
                              void* d_out, int out_size, void* d_ws, size_t ws_size,
                              hipStream_t stream) {
  const float* image    = (const float*)d_in[0];
  const float* geometry = (const float*)d_in[1];
  const float* bw       = (const float*)d_in[2];
  const float* bb       = (const float*)d_in[3];
  const float* fw       = (const float*)d_in[4];
  const float* fb       = (const float*)d_in[5];
  const float* mb       = (const float*)d_in[6];
  float* out = (float*)d_out;
  char* ws = (char*)d_ws;

  float* wgt     = (float*)(ws);                  // 8 KB
  float* qsq     = (float*)(ws + 8192);           // 8 KB
  float* msq     = (float*)(ws + 16384);          // 256 KB
  float* fwp     = (float*)(ws + 278528);         // 270336 B
  short* flatb   = (short*)(ws + 548864);         // 1 MB
  float* partial = (float*)(ws + 1597440);        // 256 KB [2048][32]
  short* mbb     = (short*)(ws + 1859584);        // 32 MB  [65536][256] bf16

  hipLaunchKernelGGL(k_repack_fw, dim3(264),     dim3(256), 0, stream, fw, fwp);
  hipLaunchKernelGGL(k_prep,      dim3(8448),    dim3(512), 0, stream,
                     image, geometry, bw, bb, fwp, fb, mb, flatb, qsq, wgt, mbb, msq);
  hipLaunchKernelGGL(k_distmin,   dim3(32, 16),  dim3(256), 0, stream, flatb, mbb, qsq, msq, partial);
  hipLaunchKernelGGL(k_final,     dim3(8),       dim3(256), 0, stream, partial, wgt, out);
}

// Round 7
// 221.463 us; speedup vs baseline: 1.0370x; 1.0370x over previous
//
#include <hip/hip_runtime.h>
#include <hip/hip_bf16.h>
#include <stdint.h>

typedef __attribute__((ext_vector_type(8))) short bf16x8;
typedef __attribute__((ext_vector_type(4))) float f32x4;

#define NP 2048
#define NBANK 65536
#define NCHUNKS 32
#define CHUNK 2048
#define SUBR 64
#define NSUB 32
#define CF 261

__device__ inline short f2bf(float f) {
  __hip_bfloat16 h = __float2bfloat16(f);
  return *reinterpret_cast<short*>(&h);
}

// ---------------- fw repack: [256][261] -> [256][264] (16B rows, zero pad) --
__global__ __launch_bounds__(256) void k_repack_fw(
    const float* __restrict__ fw, float* __restrict__ fwp)
{
  int idx = blockIdx.x * 256 + threadIdx.x;      // 256*264 = 67584
  int o = idx / 264, c = idx % 264;
  fwp[idx] = (c < CF) ? fw[(size_t)o * CF + c] : 0.f;
}

// ---------------- prep: conv+resize+fusion (blocks 0..255) ------------------
// ----------------       bank->bf16+norms   (blocks 256..8447) ---------------
// conv/fusion inner loops use wave-uniform float4 LDS reads (broadcast, free)
// instead of per-FMA scalar LDS reads (R6: ~2600 scalar ds_read per thread).
__global__ __launch_bounds__(512) void k_prep(
    const float* __restrict__ image, const float* __restrict__ geometry,
    const float* __restrict__ bw, const float* __restrict__ bb,
    const float* __restrict__ fwp, const float* __restrict__ fb,
    const float* __restrict__ mb,
    short* __restrict__ flatb, float* __restrict__ qsq, float* __restrict__ wgt,
    short* __restrict__ mbb, float* __restrict__ msq)
{
  __shared__ __align__(16) float patch[1536];
  __shared__ __align__(16) float fusedS[8][264];
  __shared__ float gv[40][8];
  __shared__ float gw[40][8];
  __shared__ float redS[8][8];
  int t = threadIdx.x;
  int bid = blockIdx.x;

  if (bid >= 256) {                       // ---- bank prep: 8 rows/block ----
    int row = (bid - 256) * 8 + (t >> 6);
    int lane = t & 63;
    float4 v = ((const float4*)(mb + (size_t)row * 256))[lane];
    short4 o; o.x = f2bf(v.x); o.y = f2bf(v.y); o.z = f2bf(v.z); o.w = f2bf(v.w);
    ((short4*)(mbb + (size_t)row * 256))[lane] = o;
    float s = v.x*v.x + v.y*v.y + v.z*v.z + v.w*v.w;
    #pragma unroll
    for (int m = 1; m < 64; m <<= 1) s += __shfl_xor(s, m);
    if (lane == 0) msq[row] = s;
    return;
  }

  // ---- conv part: block = (b, h, w-quad of 8 positions), 512 threads ----
  int b = bid >> 7, rem = bid & 127, h = rem >> 2, w0 = (rem & 3) * 8;

  #pragma unroll
  for (int j = 0; j < 3; j++) {           // stage 3x8x64 image patch
    int idx = t + j * 512;
    int c = idx >> 9, r = (idx >> 6) & 7, col = idx & 63;
    patch[idx] = image[(((size_t)(b*3 + c) * 256) + 8*h + r) * 256 + 8*w0 + col];
  }
  if (t >= 320 && t < 344) {              // zero pad fused[i][261..263]
    int i = (t - 320) / 3, c = 261 + (t - 320) % 3;
    fusedS[i][c] = 0.f;
  }
  if (t < 320) {                          // geo resize partials (8 subs/value)
    int v = t >> 3, sub = t & 7;
    int i = v / 5, cg = v % 5;
    int jj = w0 + i;
    float val = 0.f, ws = 0.f;
    const float* gch = geometry + (size_t)(b*5 + cg) * 65536;
    #pragma unroll
    for (int rr = 0; rr < 2; rr++) {
      int r = sub * 2 + rr;
      int gr = 8*h - 4 + r;
      float wr = 1.f - fabsf((float)r - 7.5f) * 0.125f;
      if (gr >= 0 && gr < 256) {
        const float* grow = gch + (size_t)gr * 256;
        for (int c = 0; c < 16; c++) {
          int gc = 8*jj - 4 + c;
          if (gc >= 0 && gc < 256) {
            float wc_ = 1.f - fabsf((float)c - 7.5f) * 0.125f;
            val += wr * wc_ * grow[gc];
            ws  += wr * wc_;
          }
        }
      }
    }
    gv[v][sub] = val; gw[v][sub] = ws;
  }
  __syncthreads();
  if (t < 40) {                           // combine resize partials
    int i = t / 5, cg = t % 5;
    float sv = 0.f, sw = 0.f;
    #pragma unroll
    for (int u = 0; u < 8; u++) { sv += gv[t][u]; sw += gw[t][u]; }
    fusedS[i][256 + cg] = sv / sw;
  }

  int g = t >> 8, o = t & 255;            // group g: positions 4g..4g+3
  float a4[4] = {0.f, 0.f, 0.f, 0.f};
  const float4* wo4 = (const float4*)(bw + (size_t)o * 192);
  for (int cr = 0; cr < 24; cr++) {       // conv 8x8 s8, broadcast LDS float4
    const float4* prow4 = (const float4*)&patch[cr * 64 + g * 32];
    float4 wA = wo4[cr*2], wB = wo4[cr*2 + 1];
    #pragma unroll
    for (int i4 = 0; i4 < 4; i4++) {
      float4 p0 = prow4[i4*2], p1 = prow4[i4*2 + 1];
      a4[i4] += wA.x*p0.x + wA.y*p0.y + wA.z*p0.z + wA.w*p0.w
              + wB.x*p1.x + wB.y*p1.y + wB.z*p1.z + wB.w*p1.w;
    }
  }
  float bias = bb[o];
  #pragma unroll
  for (int i4 = 0; i4 < 4; i4++) fusedS[g*4 + i4][o] = fmaxf(a4[i4] + bias, 0.f);
  __syncthreads();

  #pragma unroll
  for (int i4 = 0; i4 < 4; i4++) a4[i4] = 0.f;
  const float4* fwo4 = (const float4*)(fwp + (size_t)o * 264);
  for (int c4 = 0; c4 < 66; c4++) {       // fusion matmul, broadcast LDS float4
    float4 w4 = fwo4[c4];
    #pragma unroll
    for (int i4 = 0; i4 < 4; i4++) {
      float4 f4 = *(const float4*)&fusedS[g*4 + i4][c4*4];
      a4[i4] += w4.x*f4.x + w4.y*f4.y + w4.z*f4.z + w4.w*f4.w;
    }
  }
  float fbias = fb[o];
  int lane = t & 63, wid = t >> 6;
  #pragma unroll
  for (int i4 = 0; i4 < 4; i4++) {
    a4[i4] += fbias;
    int p = b*1024 + h*32 + w0 + g*4 + i4;
    flatb[(size_t)p * 256 + o] = f2bf(a4[i4]);
    float s = a4[i4] * a4[i4];
    #pragma unroll
    for (int m = 1; m < 64; m <<= 1) s += __shfl_xor(s, m);
    if (lane == 0) redS[g*4 + i4][wid & 3] = s;
  }
  __syncthreads();
  if (t < 8) {
    float s = redS[t][0] + redS[t][1] + redS[t][2] + redS[t][3];
    int p = b*1024 + h*32 + w0 + t;
    qsq[p] = s;
    float den = fusedS[t][256+3], opa = fusedS[t][256+2], ani = fusedS[t][256+4];
    float base2 = 0.5f*den + 0.25f*(1.f - opa) + 0.25f*ani;
    wgt[p] = 1.f + 1.f/(1.f + expf(-4.f*(base2 - 0.5f)));
  }
}

// ---------------- GEMM-min v6: R3's winning loop + conflict-free LDS --------
// Exactly R3's structure (best measured: 72us, MfmaUtil 39%): per iteration
// STAGE(next) -> compute 64 MFMA -> ONE __syncthreads (compiler drains).
// 2 blocks/CU provide the overlap (one computes while the other drains).
// Only change vs R3: fragment-order LDS (R4's verified mapping, 0 conflicts)
// replaces the XOR swizzle that cost 4.19M conflict cycles.
// LDS slot S (16B) of a 32KB subtile: l15=S&15, l4=(S>>4)&3, ks=(S>>6)&7,
// h=(S>>9)&1, wc=S>>10 -> holds B-row (wc*32+h*16+l15), bytes ks*64+l4*16.
__global__ __launch_bounds__(256, 2) void k_distmin(
    const short* __restrict__ Aq, const short* __restrict__ Bb,
    const float* __restrict__ qsq, const float* __restrict__ msq,
    float* __restrict__ partial)
{
  __shared__ __align__(16) unsigned char sB[2][32768];
  __shared__ float red[2][128];
  int t = threadIdx.x;
  int lane = t & 63, wid = t >> 6;
  int wr = wid >> 1, wc = wid & 1;
  const int l15 = lane & 15, l4 = lane >> 4;
  int nc = blockIdx.x, mt = blockIdx.y;
  int m0 = mt * 128;
  const size_t nchunk0 = (size_t)nc * CHUNK;
  const unsigned char* Bbyte = (const unsigned char*)Bb + nchunk0 * 512;
  const unsigned char* Abyte = (const unsigned char*)Aq;

  // per-lane loop-invariant global source offsets for the 8 stage instrs
  int soff[8];
  #pragma unroll
  for (int j = 0; j < 8; j++) {
    int sh = j * 4 + wid;                  // 0..31
    int ks = sh & 7, hh = (sh >> 3) & 1, wcs = sh >> 4;
    soff[j] = (wcs * 32 + hh * 16 + l15) * 512 + ks * 64 + l4 * 16;
  }

  // A tile -> registers/AGPRs (unified file; compiler's choice)
  bf16x8 af[4][8];
  #pragma unroll
  for (int mi = 0; mi < 4; mi++)
    #pragma unroll
    for (int ks = 0; ks < 8; ks++)
      af[mi][ks] = *(const bf16x8*)(Abyte +
          (size_t)(m0 + wr*64 + mi*16 + l15) * 512 + ks*64 + l4*16);

  float vmin[4][4];
  #pragma unroll
  for (int mi = 0; mi < 4; mi++)
    #pragma unroll
    for (int r = 0; r < 4; r++) vmin[mi][r] = 3.4e38f;

#define STAGE(bufsel, sidx) do {                                              \
    const unsigned char* gb_ = Bbyte + (size_t)(sidx) * 32768;                \
    unsigned char* lb_ = &sB[bufsel][0] + wid * 1024;                         \
    _Pragma("unroll")                                                         \
    for (int j_ = 0; j_ < 8; j_++) {                                          \
      __builtin_amdgcn_global_load_lds(                                       \
        (const __attribute__((address_space(1))) unsigned int*)(gb_ + soff[j_]), \
        (__attribute__((address_space(3))) unsigned int*)(lb_ + j_*4096),     \
        16, 0, 0);                                                            \
    }                                                                         \
  } while (0)

  STAGE(0, 0);
  __syncthreads();

  int cur = 0;
  for (int s = 0; s < NSUB; s++) {
    if (s + 1 < NSUB) STAGE(cur ^ 1, s + 1);
    const size_t nb = nchunk0 + (size_t)s * SUBR;
    float msq0 = msq[nb + wc * 32 + l15];
    float msq1 = msq[nb + wc * 32 + 16 + l15];
    const unsigned char* buf = &sB[cur][0] + wc * 16384;

    f32x4 acc[4][2];
    #pragma unroll
    for (int mi = 0; mi < 4; mi++) {
      acc[mi][0] = (f32x4){0.f, 0.f, 0.f, 0.f};
      acc[mi][1] = (f32x4){0.f, 0.f, 0.f, 0.f};
    }
    #pragma unroll
    for (int ks = 0; ks < 8; ks++) {
      bf16x8 b0 = *(const bf16x8*)(buf + ks*1024 + l4*256 + l15*16);
      bf16x8 b1 = *(const bf16x8*)(buf + 8192 + ks*1024 + l4*256 + l15*16);
      #pragma unroll
      for (int mi = 0; mi < 4; mi++) {
        acc[mi][0] = __builtin_amdgcn_mfma_f32_16x16x32_bf16(af[mi][ks], b0, acc[mi][0], 0, 0, 0);
        acc[mi][1] = __builtin_amdgcn_mfma_f32_16x16x32_bf16(af[mi][ks], b1, acc[mi][1], 0, 0, 0);
      }
    }
    #pragma unroll
    for (int mi = 0; mi < 4; mi++)
      #pragma unroll
      for (int r = 0; r < 4; r++) {
        float v = fminf(msq0 - 2.f*acc[mi][0][r], msq1 - 2.f*acc[mi][1][r]);
        vmin[mi][r] = fminf(vmin[mi][r], v);
      }
    __syncthreads();
    cur ^= 1;
  }
#undef STAGE

  // deferred cross-lane min over the 16 l15 columns
  #pragma unroll
  for (int mi = 0; mi < 4; mi++)
    #pragma unroll
    for (int r = 0; r < 4; r++) {
      float v = vmin[mi][r];
      v = fminf(v, __shfl_xor(v, 1));
      v = fminf(v, __shfl_xor(v, 2));
      v = fminf(v, __shfl_xor(v, 4));
      v = fminf(v, __shfl_xor(v, 8));
      if (l15 == 0) red[wc][wr * 64 + mi * 16 + l4 * 4 + r] = v;
    }
  __syncthreads();
  if (t < 128) {
    float v = fminf(red[0][t], red[1][t]);
    float d2 = qsq[m0 + t] + v;
    partial[(size_t)(m0 + t) * NCHUNKS + nc] = fmaxf(d2, 0.f);
  }
}

// ---------------- final min + sqrt + geo weight -----------------------------
__global__ __launch_bounds__(256) void k_final(
    const float* __restrict__ partial, const float* __restrict__ wgt,
    float* __restrict__ out)
{
  int q = blockIdx.x * 256 + threadIdx.x;        // 2048
  const float4* p = (const float4*)(partial + (size_t)q * NCHUNKS);
  float v = 3.4e38f;
  #pragma unroll
  for (int j = 0; j < 8; j++) {
    float4 x = p[j];
    v = fminf(v, fminf(fminf(x.x, x.y), fminf(x.z, x.w)));
  }
  float sp = sqrtf(v);
  out[q] = sp;
  out[NP + q] = sp * wgt[q];
}

extern "C" void kernel_launch(void* const* d_in, const int* in_sizes, int n_in,
                              void* d_out, int out_size, void* d_ws, size_t ws_size,
                              hipStream_t stream) {
  const float* image    = (const float*)d_in[0];
  const float* geometry = (const float*)d_in[1];
  const float* bw       = (const float*)d_in[2];
  const float* bb       = (const float*)d_in[3];
  const float* fw       = (const float*)d_in[4];
  const float* fb       = (const float*)d_in[5];
  const float* mb       = (const float*)d_in[6];
  float* out = (float*)d_out;
  char* ws = (char*)d_ws;

  float* wgt     = (float*)(ws);                  // 8 KB
  float* qsq     = (float*)(ws + 8192);           // 8 KB
  float* msq     = (float*)(ws + 16384);          // 256 KB
  float* fwp     = (float*)(ws + 278528);         // 270336 B
  short* flatb   = (short*)(ws + 548864);         // 1 MB
  float* partial = (float*)(ws + 1597440);        // 256 KB [2048][32]
  short* mbb     = (short*)(ws + 1859584);        // 32 MB  [65536][256] bf16

  hipLaunchKernelGGL(k_repack_fw, dim3(264),     dim3(256), 0, stream, fw, fwp);
  hipLaunchKernelGGL(k_prep,      dim3(8448),    dim3(512), 0, stream,
                     image, geometry, bw, bb, fwp, fb, mb, flatb, qsq, wgt, mbb, msq);
  hipLaunchKernelGGL(k_distmin,   dim3(32, 16),  dim3(256), 0, stream, flatb, mbb, qsq, msq, partial);
  hipLaunchKernelGGL(k_final,     dim3(8),       dim3(256), 0, stream, partial, wgt, out);
}

// Round 8
// 199.163 us; speedup vs baseline: 1.1531x; 1.1120x over previous
//
#include <hip/hip_runtime.h>
#include <hip/hip_bf16.h>
#include <stdint.h>

typedef __attribute__((ext_vector_type(8))) short bf16x8;
typedef __attribute__((ext_vector_type(4))) float f32x4;

#define NP 2048
#define NBANK 65536
#define NCHUNKS 32
#define CHUNK 2048
#define SUBR 64
#define NSUB 32
#define CF 261

__device__ inline short f2bf(float f) {
  __hip_bfloat16 h = __float2bfloat16(f);
  return *reinterpret_cast<short*>(&h);
}

// ---------------- fw repack: [256][261] -> [256][264] (16B rows, zero pad) --
__global__ __launch_bounds__(256) void k_repack_fw(
    const float* __restrict__ fw, float* __restrict__ fwp)
{
  int idx = blockIdx.x * 256 + threadIdx.x;      // 256*264 = 67584
  int o = idx / 264, c = idx % 264;
  fwp[idx] = (c < CF) ? fw[(size_t)o * CF + c] : 0.f;
}

// ---------------- prep ------------------------------------------------------
// blocks 0..255: conv(8x8 s8)+relu + antialiased resize + fusion matmul
// blocks 256..1279: bank -> bf16 in FRAGMENT-TILED layout + row norms.
// Tiled layout (32KB per 64-row subtile): 16B slot (c, l4, l15) at byte
// c*1024 + l4*256 + l15*16 holds bank row (c>>4)*32 + ((c>>3)&1)*16 + l15,
// k-bytes (c&7)*64 + l4*16 .. +16. This makes k_distmin's staging an
// identity memcpy (contiguous global) while LDS reads stay dense.
__global__ __launch_bounds__(512) void k_prep(
    const float* __restrict__ image, const float* __restrict__ geometry,
    const float* __restrict__ bw, const float* __restrict__ bb,
    const float* __restrict__ fwp, const float* __restrict__ fb,
    const float* __restrict__ mb,
    short* __restrict__ flatb, float* __restrict__ qsq, float* __restrict__ wgt,
    short* __restrict__ mbb, float* __restrict__ msq)
{
  __shared__ __align__(16) unsigned char shmem[32768];
  int t = threadIdx.x;
  int bid = blockIdx.x;

  if (bid >= 256) {                       // ---- bank prep: 64 rows/block ----
    int s = bid - 256;                    // subtile id, 0..1023
    int r = t >> 3, q = t & 7;            // row-in-subtile, k-octant
    int wcs = r >> 5, hh = (r >> 4) & 1, l15r = r & 15;
    const float* src = mb + ((size_t)s * 64 + r) * 256;
    float s2 = 0.f;
    #pragma unroll
    for (int i = 0; i < 8; i++) {
      float4 v = *(const float4*)(src + q * 4 + i * 32);  // coalesced
      short4 o; o.x = f2bf(v.x); o.y = f2bf(v.y); o.z = f2bf(v.z); o.w = f2bf(v.w);
      int kbyte = q * 8 + i * 64;
      int ks = kbyte >> 6, l4 = (kbyte >> 4) & 3, b8 = kbyte & 8;
      int c = wcs * 16 + hh * 8 + ks;
      *(short4*)(shmem + c * 1024 + l4 * 256 + l15r * 16 + b8) = o;
      s2 += v.x * v.x + v.y * v.y + v.z * v.z + v.w * v.w;
    }
    s2 += __shfl_xor(s2, 1); s2 += __shfl_xor(s2, 2); s2 += __shfl_xor(s2, 4);
    if (q == 0) msq[(size_t)s * 64 + r] = s2;
    __syncthreads();
    unsigned char* dstg = (unsigned char*)mbb + (size_t)s * 32768;
    #pragma unroll
    for (int i = 0; i < 4; i++) {         // coalesced tiled write-out
      int S = t + i * 512;
      *(float4*)(dstg + S * 16) = *(const float4*)(shmem + S * 16);
    }
    return;
  }

  // ---- conv part: block = (b, h, w-quad of 8 positions), 512 threads ----
  float* patch = (float*)shmem;                           // 1536 floats
  float (*fusedS)[264] = (float (*)[264])(shmem + 6144);  // 8x264
  float (*gv)[8] = (float (*)[8])(shmem + 14592);         // 40x8
  float (*gw)[8] = (float (*)[8])(shmem + 15872);         // 40x8
  float (*redS)[8] = (float (*)[8])(shmem + 17152);       // 8x8

  int b = bid >> 7, rem = bid & 127, h = rem >> 2, w0 = (rem & 3) * 8;

  #pragma unroll
  for (int j = 0; j < 3; j++) {           // stage 3x8x64 image patch
    int idx = t + j * 512;
    int c = idx >> 9, r = (idx >> 6) & 7, col = idx & 63;
    patch[idx] = image[(((size_t)(b*3 + c) * 256) + 8*h + r) * 256 + 8*w0 + col];
  }
  if (t >= 320 && t < 344) {              // zero pad fused[i][261..263]
    int i = (t - 320) / 3, c = 261 + (t - 320) % 3;
    fusedS[i][c] = 0.f;
  }
  if (t < 320) {                          // geo resize partials (8 subs/value)
    int v = t >> 3, sub = t & 7;
    int i = v / 5, cg = v % 5;
    int jj = w0 + i;
    float val = 0.f, ws = 0.f;
    const float* gch = geometry + (size_t)(b*5 + cg) * 65536;
    #pragma unroll
    for (int rr = 0; rr < 2; rr++) {
      int r = sub * 2 + rr;
      int gr = 8*h - 4 + r;
      float wr = 1.f - fabsf((float)r - 7.5f) * 0.125f;
      if (gr >= 0 && gr < 256) {
        const float* grow = gch + (size_t)gr * 256;
        for (int c = 0; c < 16; c++) {
          int gc = 8*jj - 4 + c;
          if (gc >= 0 && gc < 256) {
            float wc_ = 1.f - fabsf((float)c - 7.5f) * 0.125f;
            val += wr * wc_ * grow[gc];
            ws  += wr * wc_;
          }
        }
      }
    }
    gv[v][sub] = val; gw[v][sub] = ws;
  }
  __syncthreads();
  if (t < 40) {                           // combine resize partials
    int i = t / 5, cg = t % 5;
    float sv = 0.f, sw = 0.f;
    #pragma unroll
    for (int u = 0; u < 8; u++) { sv += gv[t][u]; sw += gw[t][u]; }
    fusedS[i][256 + cg] = sv / sw;
  }

  int g = t >> 8, o = t & 255;            // group g: positions 4g..4g+3
  float a4[4] = {0.f, 0.f, 0.f, 0.f};
  const float4* wo4 = (const float4*)(bw + (size_t)o * 192);
  for (int cr = 0; cr < 24; cr++) {       // conv, broadcast LDS float4
    const float4* prow4 = (const float4*)&patch[cr * 64 + g * 32];
    float4 wA = wo4[cr*2], wB = wo4[cr*2 + 1];
    #pragma unroll
    for (int i4 = 0; i4 < 4; i4++) {
      float4 p0 = prow4[i4*2], p1 = prow4[i4*2 + 1];
      a4[i4] += wA.x*p0.x + wA.y*p0.y + wA.z*p0.z + wA.w*p0.w
              + wB.x*p1.x + wB.y*p1.y + wB.z*p1.z + wB.w*p1.w;
    }
  }
  float bias = bb[o];
  #pragma unroll
  for (int i4 = 0; i4 < 4; i4++) fusedS[g*4 + i4][o] = fmaxf(a4[i4] + bias, 0.f);
  __syncthreads();

  #pragma unroll
  for (int i4 = 0; i4 < 4; i4++) a4[i4] = 0.f;
  const float4* fwo4 = (const float4*)(fwp + (size_t)o * 264);
  for (int c4 = 0; c4 < 66; c4++) {       // fusion matmul, broadcast LDS float4
    float4 w4 = fwo4[c4];
    #pragma unroll
    for (int i4 = 0; i4 < 4; i4++) {
      float4 f4 = *(const float4*)&fusedS[g*4 + i4][c4*4];
      a4[i4] += w4.x*f4.x + w4.y*f4.y + w4.z*f4.z + w4.w*f4.w;
    }
  }
  float fbias = fb[o];
  int lane = t & 63, wid = t >> 6;
  #pragma unroll
  for (int i4 = 0; i4 < 4; i4++) {
    a4[i4] += fbias;
    int p = b*1024 + h*32 + w0 + g*4 + i4;
    flatb[(size_t)p * 256 + o] = f2bf(a4[i4]);
    float s = a4[i4] * a4[i4];
    #pragma unroll
    for (int m = 1; m < 64; m <<= 1) s += __shfl_xor(s, m);
    if (lane == 0) redS[g*4 + i4][wid & 3] = s;
  }
  __syncthreads();
  if (t < 8) {
    float s = redS[t][0] + redS[t][1] + redS[t][2] + redS[t][3];
    int p = b*1024 + h*32 + w0 + t;
    qsq[p] = s;
    float den = fusedS[t][256+3], opa = fusedS[t][256+2], ani = fusedS[t][256+4];
    float base2 = 0.5f*den + 0.25f*(1.f - opa) + 0.25f*ani;
    wgt[p] = 1.f + 1.f/(1.f + expf(-4.f*(base2 - 0.5f)));
  }
}

// ---------------- GEMM-min v7: R3 loop + tiled bank (contig stage, 0-conflict)
// R3's winning structure (72us): per iter STAGE(next) -> 64 MFMA/wave -> ONE
// __syncthreads. Bank is pre-tiled by k_prep, so each global_load_lds reads
// 1024B CONTIGUOUS global (8 full lines, like R3) into linear LDS, and the
// compute reads are dense ds_read_b128 (0 conflicts, like R7).
__global__ __launch_bounds__(256, 2) void k_distmin(
    const short* __restrict__ Aq, const short* __restrict__ Bb,
    const float* __restrict__ qsq, const float* __restrict__ msq,
    float* __restrict__ partial)
{
  __shared__ __align__(16) unsigned char sB[2][32768];
  __shared__ float red[2][128];
  int t = threadIdx.x;
  int lane = t & 63, wid = t >> 6;
  int wr = wid >> 1, wc = wid & 1;
  const int l15 = lane & 15, l4 = lane >> 4;
  int nc = blockIdx.x, mt = blockIdx.y;
  int m0 = mt * 128;
  const size_t nchunk0 = (size_t)nc * CHUNK;
  const unsigned char* Bbyte = (const unsigned char*)Bb + nchunk0 * 512;
  const unsigned char* Abyte = (const unsigned char*)Aq;

  // A tile -> registers/AGPRs (unified file; compiler's choice)
  bf16x8 af[4][8];
  #pragma unroll
  for (int mi = 0; mi < 4; mi++)
    #pragma unroll
    for (int ks = 0; ks < 8; ks++)
      af[mi][ks] = *(const bf16x8*)(Abyte +
          (size_t)(m0 + wr*64 + mi*16 + l15) * 512 + ks*64 + l4*16);

  float vmin[4][4];
  #pragma unroll
  for (int mi = 0; mi < 4; mi++)
    #pragma unroll
    for (int r = 0; r < 4; r++) vmin[mi][r] = 3.4e38f;

#define STAGE(bufsel, sidx) do {                                              \
    const unsigned char* gb_ = Bbyte + (size_t)(sidx) * 32768 + wid * 1024 + lane * 16; \
    unsigned char* lb_ = &sB[bufsel][0] + wid * 1024;                         \
    _Pragma("unroll")                                                         \
    for (int j_ = 0; j_ < 8; j_++) {                                          \
      __builtin_amdgcn_global_load_lds(                                       \
        (const __attribute__((address_space(1))) unsigned int*)(gb_ + j_*4096), \
        (__attribute__((address_space(3))) unsigned int*)(lb_ + j_*4096),     \
        16, 0, 0);                                                            \
    }                                                                         \
  } while (0)

  STAGE(0, 0);
  __syncthreads();

  int cur = 0;
  for (int s = 0; s < NSUB; s++) {
    if (s + 1 < NSUB) STAGE(cur ^ 1, s + 1);
    const size_t nb = nchunk0 + (size_t)s * SUBR;
    float msq0 = msq[nb + wc * 32 + l15];
    float msq1 = msq[nb + wc * 32 + 16 + l15];
    const unsigned char* buf = &sB[cur][0] + wc * 16384;

    f32x4 acc[4][2];
    #pragma unroll
    for (int mi = 0; mi < 4; mi++) {
      acc[mi][0] = (f32x4){0.f, 0.f, 0.f, 0.f};
      acc[mi][1] = (f32x4){0.f, 0.f, 0.f, 0.f};
    }
    #pragma unroll
    for (int ks = 0; ks < 8; ks++) {
      bf16x8 b0 = *(const bf16x8*)(buf + ks*1024 + l4*256 + l15*16);
      bf16x8 b1 = *(const bf16x8*)(buf + 8192 + ks*1024 + l4*256 + l15*16);
      #pragma unroll
      for (int mi = 0; mi < 4; mi++) {
        acc[mi][0] = __builtin_amdgcn_mfma_f32_16x16x32_bf16(af[mi][ks], b0, acc[mi][0], 0, 0, 0);
        acc[mi][1] = __builtin_amdgcn_mfma_f32_16x16x32_bf16(af[mi][ks], b1, acc[mi][1], 0, 0, 0);
      }
    }
    #pragma unroll
    for (int mi = 0; mi < 4; mi++)
      #pragma unroll
      for (int r = 0; r < 4; r++) {
        float v = fminf(msq0 - 2.f*acc[mi][0][r], msq1 - 2.f*acc[mi][1][r]);
        vmin[mi][r] = fminf(vmin[mi][r], v);
      }
    __syncthreads();
    cur ^= 1;
  }
#undef STAGE

  // deferred cross-lane min over the 16 l15 columns
  #pragma unroll
  for (int mi = 0; mi < 4; mi++)
    #pragma unroll
    for (int r = 0; r < 4; r++) {
      float v = vmin[mi][r];
      v = fminf(v, __shfl_xor(v, 1));
      v = fminf(v, __shfl_xor(v, 2));
      v = fminf(v, __shfl_xor(v, 4));
      v = fminf(v, __shfl_xor(v, 8));
      if (l15 == 0) red[wc][wr * 64 + mi * 16 + l4 * 4 + r] = v;
    }
  __syncthreads();
  if (t < 128) {
    float v = fminf(red[0][t], red[1][t]);
    float d2 = qsq[m0 + t] + v;
    partial[(size_t)(m0 + t) * NCHUNKS + nc] = fmaxf(d2, 0.f);
  }
}

// ---------------- final min + sqrt + geo weight -----------------------------
__global__ __launch_bounds__(256) void k_final(
    const float* __restrict__ partial, const float* __restrict__ wgt,
    float* __restrict__ out)
{
  int q = blockIdx.x * 256 + threadIdx.x;        // 2048
  const float4* p = (const float4*)(partial + (size_t)q * NCHUNKS);
  float v = 3.4e38f;
  #pragma unroll
  for (int j = 0; j < 8; j++) {
    float4 x = p[j];
    v = fminf(v, fminf(fminf(x.x, x.y), fminf(x.z, x.w)));
  }
  float sp = sqrtf(v);
  out[q] = sp;
  out[NP + q] = sp * wgt[q];
}

extern "C" void kernel_launch(void* const* d_in, const int* in_sizes, int n_in,
                              void* d_out, int out_size, void* d_ws, size_t ws_size,
                              hipStream_t stream) {
  const float* image    = (const float*)d_in[0];
  const float* geometry = (const float*)d_in[1];
  const float* bw       = (const float*)d_in[2];
  const float* bb       = (const float*)d_in[3];
  const float* fw       = (const float*)d_in[4];
  const float* fb       = (const float*)d_in[5];
  const float* mb       = (const float*)d_in[6];
  float* out = (float*)d_out;
  char* ws = (char*)d_ws;

  float* wgt     = (float*)(ws);                  // 8 KB
  float* qsq     = (float*)(ws + 8192);           // 8 KB
  float* msq     = (float*)(ws + 16384);          // 256 KB
  float* fwp     = (float*)(ws + 278528);         // 270336 B
  short* flatb   = (short*)(ws + 548864);         // 1 MB
  float* partial = (float*)(ws + 1597440);        // 256 KB [2048][32]
  short* mbb     = (short*)(ws + 1859584);        // 32 MB  [65536][256] bf16, TILED

  hipLaunchKernelGGL(k_repack_fw, dim3(264),     dim3(256), 0, stream, fw, fwp);
  hipLaunchKernelGGL(k_prep,      dim3(1280),    dim3(512), 0, stream,
                     image, geometry, bw, bb, fwp, fb, mb, flatb, qsq, wgt, mbb, msq);
  hipLaunchKernelGGL(k_distmin,   dim3(32, 16),  dim3(256), 0, stream, flatb, mbb, qsq, msq, partial);
  hipLaunchKernelGGL(k_final,     dim3(8),       dim3(256), 0, stream, partial, wgt, out);
}